// Round 5
// baseline (1192.441 us; speedup 1.0000x reference)
//
#include <hip/hip_runtime.h>
#include <hip/hip_bf16.h>
#include <math.h>

// Problem constants (fixed by reference)
constexpr int N_NODES = 100000;
constexpr int N_EDGES = 1600000;
constexpr int IN_CH   = 61;
constexpr float BN_EPS = 1e-5f;
constexpr int NPART   = 32;   // atomic spread slots

// stats layout (floats), total 4352:
//  [0..63]    mu_h        [64..127] rs_h
//  [128] gmu  [129] grs
//  [192 .. 192+NPART*128)          part_h: slot s -> [192+s*128+c]=sum_c, [+64+c]=sumsq_c
//  [4288 .. 4288+NPART*2)          part_g: slot s -> [4288+2s]=sum, [4288+2s+1]=sumsq
constexpr int S_PH = 192;
constexpr int S_PG = 192 + NPART * 128;      // 4288
constexpr int S_TOT = S_PG + NPART * 2;      // 4352

__device__ __forceinline__ float silu(float x) { return x / (1.0f + expf(-x)); }

__device__ __forceinline__ float bf2f(unsigned v) { return __uint_as_float(v << 16); }
__device__ __forceinline__ unsigned f2bf(float f) {
    unsigned u = __float_as_uint(f);
    return (u + 0x7FFFu + ((u >> 16) & 1u)) >> 16;   // RNE
}

// Shared per-edge gather + [1x64]x[64x64] matvec. Returns false (acc=0) on bad index.
__device__ __forceinline__ bool edge_gemm(
    int e, const float* __restrict__ x, const float* __restrict__ pos,
    const int* __restrict__ ei, const float* __restrict__ W1,
    const float* __restrict__ b1, float* acc, int* jd_out)
{
    int js = ei[e];
    int jd = ei[N_EDGES + e];
    *jd_out = jd;
    bool valid = ((unsigned)js < (unsigned)N_NODES) && ((unsigned)jd < (unsigned)N_NODES);
    #pragma unroll
    for (int c = 0; c < 64; ++c) acc[c] = 0.0f;
    if (!valid) return false;

    float f[64];
    const float* xr = x + (size_t)js * IN_CH;
    #pragma unroll
    for (int k = 0; k < IN_CH; ++k) f[k] = xr[k];
    #pragma unroll
    for (int j = 0; j < 3; ++j) f[IN_CH + j] = pos[js * 3 + j] - pos[jd * 3 + j];

    #pragma unroll
    for (int c = 0; c < 64; ++c) acc[c] = b1[c];
    #pragma unroll 4
    for (int k = 0; k < 64; ++k) {
        float fk = f[k];
        #pragma unroll
        for (int c = 0; c < 64; ++c) acc[c] += fk * W1[k * 64 + c];
    }
    return true;
}

// ---- K0: init stats + deg ----
__global__ __launch_bounds__(256) void k_init(float* stats, int* deg) {
    int i = blockIdx.x * 256 + threadIdx.x;
    if (i < S_TOT) stats[i] = 0.0f;
    if (i < N_NODES) deg[i] = 0;
}

// ---- K1: per-edge GEMM. MODE 0: write f32 h. MODE 1: write bf16 h.
//          MODE 2: no h; accumulate per-channel stats directly. Always: deg histogram.
template<int MODE>
__global__ __launch_bounds__(256) void k_edge(
    const float* __restrict__ x, const float* __restrict__ pos,
    const int* __restrict__ ei, const float* __restrict__ W1,
    const float* __restrict__ b1, float* __restrict__ stats,
    int* __restrict__ deg, void* __restrict__ h, size_t h_cap)
{
    int e = blockIdx.x * 256 + threadIdx.x;   // grid exact: E/256
    float acc[64];
    int jd;
    bool valid = edge_gemm(e, x, pos, ei, W1, b1, acc, &jd);
    if (valid) atomicAdd(&deg[jd], 1);

    if constexpr (MODE == 0) {
        if ((size_t)(e + 1) * 256 <= h_cap) {
            float4* hp = (float4*)((char*)h + (size_t)e * 256);
            #pragma unroll
            for (int i = 0; i < 16; ++i)
                hp[i] = make_float4(acc[4*i], acc[4*i+1], acc[4*i+2], acc[4*i+3]);
        }
    } else if constexpr (MODE == 1) {
        if ((size_t)(e + 1) * 128 <= h_cap) {
            unsigned wb[32];
            #pragma unroll
            for (int i = 0; i < 32; ++i)
                wb[i] = f2bf(acc[2*i]) | (f2bf(acc[2*i+1]) << 16);
            uint4* hp = (uint4*)((char*)h + (size_t)e * 128);
            #pragma unroll
            for (int j = 0; j < 8; ++j)
                hp[j] = make_uint4(wb[4*j], wb[4*j+1], wb[4*j+2], wb[4*j+3]);
        }
    } else {
        __shared__ float ls[128];
        if (threadIdx.x < 128) ls[threadIdx.x] = 0.0f;
        __syncthreads();
        #pragma unroll
        for (int c = 0; c < 64; ++c) {
            atomicAdd(&ls[c], acc[c]);
            atomicAdd(&ls[64 + c], acc[c] * acc[c]);
        }
        __syncthreads();
        if (threadIdx.x < 128)
            atomicAdd(&stats[S_PH + (blockIdx.x & (NPART-1)) * 128 + threadIdx.x],
                      ls[threadIdx.x]);
    }
}

// ---- K2: per-channel sum/sumsq streaming over h (modes 0/1 only) ----
template<int MODE>
__global__ __launch_bounds__(256) void k_stats(const void* __restrict__ h,
                                               float* __restrict__ stats)
{
    constexpr int VEC = (MODE == 0) ? 4 : 8;
    const size_t nvec = (size_t)N_EDGES * 64 / VEC;
    size_t stride = (size_t)gridDim.x * 256;            // 262144 (x VEC elems: mult of 64)
    size_t g0 = (size_t)blockIdx.x * 256 + threadIdx.x;
    int c0 = (int)((g0 * VEC) & 63);
    float sum[VEC], sq[VEC];
    #pragma unroll
    for (int j = 0; j < VEC; ++j) { sum[j] = 0.0f; sq[j] = 0.0f; }

    for (size_t v = g0; v < nvec; v += stride) {
        float vals[VEC];
        if constexpr (MODE == 0) {
            float4 t = ((const float4*)h)[v];
            vals[0] = t.x; vals[1] = t.y; vals[2] = t.z; vals[3] = t.w;
        } else {
            uint4 t = ((const uint4*)h)[v];
            vals[0] = bf2f(t.x & 0xFFFF); vals[1] = bf2f(t.x >> 16);
            vals[2] = bf2f(t.y & 0xFFFF); vals[3] = bf2f(t.y >> 16);
            vals[4] = bf2f(t.z & 0xFFFF); vals[5] = bf2f(t.z >> 16);
            vals[6] = bf2f(t.w & 0xFFFF); vals[7] = bf2f(t.w >> 16);
        }
        #pragma unroll
        for (int j = 0; j < VEC; ++j) { sum[j] += vals[j]; sq[j] += vals[j] * vals[j]; }
    }
    __shared__ float ls[128];
    if (threadIdx.x < 128) ls[threadIdx.x] = 0.0f;
    __syncthreads();
    #pragma unroll
    for (int j = 0; j < VEC; ++j) {
        atomicAdd(&ls[c0 + j], sum[j]);
        atomicAdd(&ls[64 + c0 + j], sq[j]);
    }
    __syncthreads();
    if (threadIdx.x < 128)
        atomicAdd(&stats[S_PH + (blockIdx.x & (NPART-1)) * 128 + threadIdx.x],
                  ls[threadIdx.x]);
}

// ---- K3: reduce part_h -> mu/rs ----
__global__ void k_bnfin(float* stats) {
    int c = threadIdx.x;
    if (c < 64) {
        float s = 0.0f, q = 0.0f;
        #pragma unroll
        for (int p = 0; p < NPART; ++p) {
            s += stats[S_PH + p * 128 + c];
            q += stats[S_PH + p * 128 + 64 + c];
        }
        float m = s / (float)N_EDGES;
        float v = q / (float)N_EDGES - m * m;
        stats[c] = m;
        stats[64 + c] = rsqrtf(v + BN_EPS);
    }
}

// ---- K4: gate_lin per edge + gate batch stats ----
template<int MODE>
__global__ __launch_bounds__(256) void k_gate(
    const void* __restrict__ h, const float* __restrict__ x,
    const float* __restrict__ pos, const int* __restrict__ ei,
    const float* __restrict__ W1, const float* __restrict__ b1,
    float* __restrict__ stats, const float* __restrict__ g1,
    const float* __restrict__ be1, const float* __restrict__ Wg,
    const float* __restrict__ bg, float* __restrict__ gate_lin, size_t h_cap)
{
    int e = blockIdx.x * 256 + threadIdx.x;   // grid exact
    float hv[64];
    if constexpr (MODE == 0) {
        if ((size_t)(e + 1) * 256 <= h_cap) {
            const float4* hp = (const float4*)((const char*)h + (size_t)e * 256);
            #pragma unroll
            for (int i = 0; i < 16; ++i) {
                float4 t = hp[i];
                hv[4*i] = t.x; hv[4*i+1] = t.y; hv[4*i+2] = t.z; hv[4*i+3] = t.w;
            }
        } else {
            #pragma unroll
            for (int c = 0; c < 64; ++c) hv[c] = 0.0f;
        }
    } else if constexpr (MODE == 1) {
        if ((size_t)(e + 1) * 128 <= h_cap) {
            const uint4* hp = (const uint4*)((const char*)h + (size_t)e * 128);
            #pragma unroll
            for (int j = 0; j < 8; ++j) {
                uint4 t = hp[j];
                hv[8*j+0] = bf2f(t.x & 0xFFFF); hv[8*j+1] = bf2f(t.x >> 16);
                hv[8*j+2] = bf2f(t.y & 0xFFFF); hv[8*j+3] = bf2f(t.y >> 16);
                hv[8*j+4] = bf2f(t.z & 0xFFFF); hv[8*j+5] = bf2f(t.z >> 16);
                hv[8*j+6] = bf2f(t.w & 0xFFFF); hv[8*j+7] = bf2f(t.w >> 16);
            }
        } else {
            #pragma unroll
            for (int c = 0; c < 64; ++c) hv[c] = 0.0f;
        }
    } else {
        int jd;
        edge_gemm(e, x, pos, ei, W1, b1, hv, &jd);
    }

    float gl = bg[0];
    #pragma unroll
    for (int c = 0; c < 64; ++c) {
        float t = (hv[c] - stats[c]) * stats[64 + c] * g1[c] + be1[c];
        gl += silu(t) * Wg[c];
    }
    gate_lin[e] = gl;

    float s1 = gl, s2 = gl * gl;
    #pragma unroll
    for (int off = 32; off >= 1; off >>= 1) {
        s1 += __shfl_xor(s1, off);
        s2 += __shfl_xor(s2, off);
    }
    __shared__ float red[8];
    int w = threadIdx.x >> 6, lane = threadIdx.x & 63;
    if (lane == 0) { red[w] = s1; red[4 + w] = s2; }
    __syncthreads();
    if (threadIdx.x == 0) {
        int slot = S_PG + (blockIdx.x & (NPART-1)) * 2;
        atomicAdd(&stats[slot], red[0] + red[1] + red[2] + red[3]);
        atomicAdd(&stats[slot + 1], red[4] + red[5] + red[6] + red[7]);
    }
}

// ---- K5: reduce part_g -> gmu/grs ----
__global__ void k_gfin(float* stats) {
    if (threadIdx.x == 0) {
        float s = 0.0f, q = 0.0f;
        for (int p = 0; p < NPART; ++p) {
            s += stats[S_PG + 2 * p];
            q += stats[S_PG + 2 * p + 1];
        }
        float m = s / (float)N_EDGES;
        float v = q / (float)N_EDGES - m * m;
        stats[128] = m;
        stats[129] = rsqrtf(v + BN_EPS);
    }
}

// ---- K6: single-block scan deg -> offs, cursor ----
__global__ __launch_bounds__(1024) void k_scan(const int* __restrict__ deg,
                                               int* __restrict__ offs,
                                               int* __restrict__ cursor)
{
    __shared__ int ps[1024];
    int t = threadIdx.x;
    const int CH = (N_NODES + 1023) / 1024;
    int lo = t * CH, hi = lo + CH;
    if (hi > N_NODES) hi = N_NODES;
    if (lo > N_NODES) lo = N_NODES;
    int s = 0;
    for (int i = lo; i < hi; ++i) s += deg[i];
    ps[t] = s;
    __syncthreads();
    for (int off = 1; off < 1024; off <<= 1) {
        int v = (t >= off) ? ps[t - off] : 0;
        __syncthreads();
        ps[t] += v;
        __syncthreads();
    }
    int run = (t == 0) ? 0 : ps[t - 1];
    for (int i = lo; i < hi; ++i) {
        offs[i] = run;
        cursor[i] = run;
        run += deg[i];
    }
    if (t == 1023) offs[N_NODES] = ps[1023];
}

// ---- K7: CSR fill ----
__global__ __launch_bounds__(256) void k_fill(const int* __restrict__ ei,
                                              int* __restrict__ cursor,
                                              int* __restrict__ elist)
{
    int e = blockIdx.x * 256 + threadIdx.x;
    int js = ei[e];
    int d = ei[N_EDGES + e];
    if ((unsigned)js >= (unsigned)N_NODES || (unsigned)d >= (unsigned)N_NODES) return;
    int p = atomicAdd(&cursor[d], 1);
    if ((unsigned)p < (unsigned)N_EDGES) elist[p] = e;
}

// ---- K8 body: wave per node, lane = channel ----
template<int MODE>
__device__ __forceinline__ void aggr_body(
    const void* __restrict__ h, size_t h_cap, const float* __restrict__ gate_lin,
    const int* __restrict__ offs, const int* __restrict__ elist,
    const int* __restrict__ ei, const float* __restrict__ x,
    const float* __restrict__ pos, const float* __restrict__ b1,
    const float* W1s, const float* __restrict__ stats,
    const float* __restrict__ g1, const float* __restrict__ be1,
    const float* __restrict__ gg, const float* __restrict__ bgb,
    float* __restrict__ out)
{
    int wid = (blockIdx.x * 256 + threadIdx.x) >> 6;
    int lane = threadIdx.x & 63;
    if (wid >= N_NODES) return;

    float mu = stats[lane], rs = stats[64 + lane];
    float gmu = stats[128], grs = stats[129];
    float ga = g1[lane], bb = be1[lane];
    float gga = gg[0], gbb = bgb[0];
    float b1v = 0.0f, pim = 0.0f;
    if constexpr (MODE == 2) {
        b1v = b1[lane];
        if (lane >= IN_CH) pim = pos[wid * 3 + (lane - IN_CH)];
    }

    int lo = offs[wid], hi = offs[wid + 1];
    float accv = 0.0f, wsum = 0.0f;
    for (int i = lo; i < hi; ++i) {
        int e = elist[i];                       // lane-uniform
        float gl = gate_lin[e];
        float tg = (gl - gmu) * grs * gga + gbb;
        float w = expf(silu(tg));               // BN-standardized: no max-shift needed
        float hval;
        if constexpr (MODE == 0) {
            if ((size_t)(e + 1) * 256 > h_cap) continue;
            hval = ((const float*)h)[(size_t)e * 64 + lane];
        } else if constexpr (MODE == 1) {
            if ((size_t)(e + 1) * 128 > h_cap) continue;
            hval = bf2f(((const unsigned short*)h)[(size_t)e * 64 + lane]);
        } else {
            int js = ei[e];
            if ((unsigned)js >= (unsigned)N_NODES) continue;   // wave-uniform
            float fl = (lane < IN_CH) ? x[(size_t)js * IN_CH + lane]
                                      : pos[js * 3 + (lane - IN_CH)] - pim;
            float a = b1v;
            #pragma unroll
            for (int k = 0; k < 64; ++k) a += __shfl(fl, k) * W1s[k * 64 + lane];
            hval = a;
        }
        float tn = (hval - mu) * rs * ga + bb;
        accv += w * silu(tn);
        wsum += w;
    }
    out[(size_t)wid * 64 + lane] = accv / (wsum + 1e-16f);
}

template<int MODE>
__global__ __launch_bounds__(256) void k_aggr(
    const void* __restrict__ h, size_t h_cap, const float* __restrict__ gate_lin,
    const int* __restrict__ offs, const int* __restrict__ elist,
    const int* __restrict__ ei, const float* __restrict__ x,
    const float* __restrict__ pos, const float* __restrict__ b1,
    const float* __restrict__ W1, const float* __restrict__ stats,
    const float* __restrict__ g1, const float* __restrict__ be1,
    const float* __restrict__ gg, const float* __restrict__ bgb,
    float* __restrict__ out)
{
    if constexpr (MODE == 2) {
        __shared__ float W1s[4096];
        for (int i = threadIdx.x; i < 4096; i += 256) W1s[i] = W1[i];
        __syncthreads();
        aggr_body<2>(h, h_cap, gate_lin, offs, elist, ei, x, pos, b1, W1s,
                     stats, g1, be1, gg, bgb, out);
    } else {
        aggr_body<MODE>(h, h_cap, gate_lin, offs, elist, ei, x, pos, b1, nullptr,
                        stats, g1, be1, gg, bgb, out);
    }
}

extern "C" void kernel_launch(void* const* d_in, const int* in_sizes, int n_in,
                              void* d_out, int out_size, void* d_ws, size_t ws_size,
                              hipStream_t stream)
{
    const float* x   = (const float*)d_in[0];
    const float* pos = (const float*)d_in[1];
    const int*   ei  = (const int*)d_in[2];
    const float* W1  = (const float*)d_in[3];
    const float* b1  = (const float*)d_in[4];
    const float* g1  = (const float*)d_in[5];
    const float* be1 = (const float*)d_in[6];
    const float* Wg  = (const float*)d_in[7];
    const float* bg  = (const float*)d_in[8];
    const float* gg  = (const float*)d_in[9];
    const float* bgb = (const float*)d_in[10];
    float* out = (float*)d_out;

    // --- adaptive ws layout: small structures first, h (if it fits) last ---
    char* base = (char*)d_ws;
    size_t off = 0;
    auto alloc = [&](size_t bytes) {
        size_t o = off;
        off = (off + bytes + 255) & ~(size_t)255;
        return o;
    };
    float* stats    = (float*)(base + alloc(S_TOT * 4));
    int*   deg      = (int*)(base + alloc((size_t)N_NODES * 4));
    int*   offs     = (int*)(base + alloc((size_t)(N_NODES + 1) * 4));
    int*   cursor   = (int*)(base + alloc((size_t)N_NODES * 4));
    int*   elist    = (int*)(base + alloc((size_t)N_EDGES * 4));
    float* gate_lin = (float*)(base + alloc((size_t)N_EDGES * 4));
    if (ws_size < off) return;                       // degenerate: can't run at all
    void*  h     = (void*)(base + off);
    size_t h_cap = ws_size - off;

    const int mode = (h_cap >= (size_t)N_EDGES * 256) ? 0
                   : (h_cap >= (size_t)N_EDGES * 128) ? 1 : 2;

    const int EB = N_EDGES / 256;            // 6250 exact
    const int NB = (N_NODES + 255) / 256;    // 391
    const int AB = (N_NODES + 3) / 4;        // 25001

    hipLaunchKernelGGL(k_init, dim3(NB), dim3(256), 0, stream, stats, deg);

    if (mode == 0) {
        hipLaunchKernelGGL(k_edge<0>, dim3(EB), dim3(256), 0, stream,
                           x, pos, ei, W1, b1, stats, deg, h, h_cap);
        hipLaunchKernelGGL(k_stats<0>, dim3(1024), dim3(256), 0, stream, h, stats);
        hipLaunchKernelGGL(k_bnfin, dim3(1), dim3(64), 0, stream, stats);
        hipLaunchKernelGGL(k_gate<0>, dim3(EB), dim3(256), 0, stream,
                           h, x, pos, ei, W1, b1, stats, g1, be1, Wg, bg, gate_lin, h_cap);
    } else if (mode == 1) {
        hipLaunchKernelGGL(k_edge<1>, dim3(EB), dim3(256), 0, stream,
                           x, pos, ei, W1, b1, stats, deg, h, h_cap);
        hipLaunchKernelGGL(k_stats<1>, dim3(1024), dim3(256), 0, stream, h, stats);
        hipLaunchKernelGGL(k_bnfin, dim3(1), dim3(64), 0, stream, stats);
        hipLaunchKernelGGL(k_gate<1>, dim3(EB), dim3(256), 0, stream,
                           h, x, pos, ei, W1, b1, stats, g1, be1, Wg, bg, gate_lin, h_cap);
    } else {
        hipLaunchKernelGGL(k_edge<2>, dim3(EB), dim3(256), 0, stream,
                           x, pos, ei, W1, b1, stats, deg, h, h_cap);
        hipLaunchKernelGGL(k_bnfin, dim3(1), dim3(64), 0, stream, stats);
        hipLaunchKernelGGL(k_gate<2>, dim3(EB), dim3(256), 0, stream,
                           h, x, pos, ei, W1, b1, stats, g1, be1, Wg, bg, gate_lin, h_cap);
    }

    hipLaunchKernelGGL(k_gfin, dim3(1), dim3(64), 0, stream, stats);
    hipLaunchKernelGGL(k_scan, dim3(1), dim3(1024), 0, stream, deg, offs, cursor);
    hipLaunchKernelGGL(k_fill, dim3(EB), dim3(256), 0, stream, ei, cursor, elist);

    if (mode == 0) {
        hipLaunchKernelGGL(k_aggr<0>, dim3(AB), dim3(256), 0, stream,
                           h, h_cap, gate_lin, offs, elist, ei, x, pos, b1, W1,
                           stats, g1, be1, gg, bgb, out);
    } else if (mode == 1) {
        hipLaunchKernelGGL(k_aggr<1>, dim3(AB), dim3(256), 0, stream,
                           h, h_cap, gate_lin, offs, elist, ei, x, pos, b1, W1,
                           stats, g1, be1, gg, bgb, out);
    } else {
        hipLaunchKernelGGL(k_aggr<2>, dim3(AB), dim3(256), 0, stream,
                           h, h_cap, gate_lin, offs, elist, ei, x, pos, b1, W1,
                           stats, g1, be1, gg, bgb, out);
    }
}